// Round 10
// baseline (8091877.344 us; speedup 1.0000x reference)
//
#include <hip/hip_runtime.h>

typedef __attribute__((ext_vector_type(8))) __bf16 bf16x8;
typedef __attribute__((ext_vector_type(4))) __bf16 bf16x4;
typedef __attribute__((ext_vector_type(4))) float f32x4;
typedef unsigned long long u64;

#define OUT_HT (64ll*512*1024)
#define OUT_CT (OUT_HT + 64*1024)
#define SPIN_BUDGET 50000000

__device__ __forceinline__ float bf2f(unsigned short u){
    union { float f; unsigned i; } c; c.i = ((unsigned)u) << 16; return c.f;
}
// sc0 = bypass L1, operate at the XCD's L2 (the coherence point for same-XCD blocks)
__device__ __forceinline__ void store32_sc0(int* p, int v){
    asm volatile("global_store_dword %0, %1, off sc0" :: "v"(p), "v"(v) : "memory");
}
__device__ __forceinline__ void store64_sc0(u64* p, u64 v){
    asm volatile("global_store_dwordx2 %0, %1, off sc0" :: "v"(p), "v"(v) : "memory");
}
__device__ __forceinline__ int load32_sc0(const int* p){
    int r;
    asm volatile("global_load_dword %0, %1, off sc0\n\ts_waitcnt vmcnt(0)"
                 : "=v"(r) : "v"(p) : "memory");
    return r;
}

// ---------------- prep: x fp32 -> bf16 (same [b][t][i] layout) ----------------
__global__ void convert_x(const float4* __restrict__ in, bf16x4* __restrict__ outp) {
    int i = blockIdx.x * 256 + threadIdx.x;
    float4 v = in[i];
    bf16x4 o;
    o[0] = (__bf16)v.x; o[1] = (__bf16)v.y; o[2] = (__bf16)v.z; o[3] = (__bf16)v.w;
    outp[i] = o;
}

// ------- prep: build W_comb [2048][4096] bf16 in MFMA-fragment-swizzled order -------
// element (k, n): n = h*4+g ; k<1024 -> W_x{g}[k][h], else W_h{g}[k-1024][h]
// frag order: wf[(((ng*64 + kc)*64 + l)<<3) + j], kc=k>>5, quad=(k>>3)&3, j=k&7,
//             ng=n>>4, l=quad*16 + (n&15)
__global__ void build_w(const float* __restrict__ Wxi, const float* __restrict__ Whi,
                        const float* __restrict__ Wxf, const float* __restrict__ Whf,
                        const float* __restrict__ Wxc, const float* __restrict__ Whc,
                        const float* __restrict__ Wxo, const float* __restrict__ Who,
                        __bf16* __restrict__ wf) {
    int idx = blockIdx.x * 256 + threadIdx.x;
    int k = idx >> 12, n = idx & 4095;
    int h = n >> 2, g = n & 3;
    const float* W;
    if (k < 1024) W = (g == 0 ? Wxi : g == 1 ? Wxf : g == 2 ? Wxc : Wxo);
    else          W = (g == 0 ? Whi : g == 1 ? Whf : g == 2 ? Whc : Who);
    float v = W[(k & 1023) * 1024 + h];
    int kc = k >> 5, quad = (k >> 3) & 3, j = k & 7;
    int ng = n >> 4, l = quad * 16 + (n & 15);
    wf[((((ng * 64) + kc) * 64 + l) << 3) + j] = (__bf16)v;
}

// ---------------- pre-pass: XG[b*512+t][4096] = x @ W_x (bf16 out, no bias) ----------------
__global__ void __launch_bounds__(256) xgemm(const __bf16* __restrict__ xbf,
                                             const __bf16* __restrict__ wf,
                                             __bf16* __restrict__ XG) {
    __shared__ __bf16 Abuf[2][64*128];   // 2 x 16 KB
    const int tid = threadIdx.x, wave = tid >> 6, lane = tid & 63;
    const int l15 = lane & 15, quad = lane >> 4;
    const int bid = blockIdx.x, ntile = bid >> 9, mtile = bid & 511;
    const size_t arow0 = (size_t)mtile * 64;

    f32x4 acc[4][4];
    for (int i = 0; i < 4; ++i)
        for (int j = 0; j < 4; ++j) acc[i][j] = (f32x4){0.f,0.f,0.f,0.f};

    auto stage = [&](int c, int bsel) {
        #pragma unroll
        for (int i = 0; i < 4; ++i) {
            int L = wave*4096 + i*1024 + lane*16;           // byte pos in 16KB tile
            int row = L >> 8;
            int kb  = (L & 255) ^ ((row & 7) << 4);         // inverse-swizzled source
            const __bf16* src = xbf + (arow0 + row)*1024 + c*128 + (kb >> 1);
            __builtin_amdgcn_global_load_lds(
                (const __attribute__((address_space(1))) unsigned*)(const void*)src,
                (__attribute__((address_space(3))) unsigned*)(void*)
                    ((char*)&Abuf[bsel][0] + wave*4096 + i*1024),
                16, 0, 0);
        }
    };

    stage(0, 0);
    #pragma unroll 1
    for (int c = 0; c < 8; ++c) {
        __syncthreads();                  // drains stage(c) (vmcnt0 at barrier)
        if (c < 7) stage(c + 1, (c + 1) & 1);   // flies during compute(c)
        const __bf16* ab = &Abuf[c & 1][0];
        #pragma unroll
        for (int kc2 = 0; kc2 < 4; ++kc2) {
            int kc = c*4 + kc2;           // x-part kc 0..31
            size_t base = ((size_t)((ntile*16 + wave*4)*64 + kc)*64 + lane)*8;
            bf16x8 b0 = *(const bf16x8*)(wf + base);
            bf16x8 b1 = *(const bf16x8*)(wf + base + 1*64*64*8);
            bf16x8 b2 = *(const bf16x8*)(wf + base + 2*64*64*8);
            bf16x8 b3 = *(const bf16x8*)(wf + base + 3*64*64*8);
            bf16x8 a[4];
            #pragma unroll
            for (int rt = 0; rt < 4; ++rt) {
                int row = rt*16 + l15;
                int kbyte = (kc2*64 + quad*16) ^ ((row & 7) << 4);
                a[rt] = *(const bf16x8*)((const char*)ab + row*256 + kbyte);
            }
            #pragma unroll
            for (int rt = 0; rt < 4; ++rt) {
                acc[rt][0] = __builtin_amdgcn_mfma_f32_16x16x32_bf16(a[rt], b0, acc[rt][0],0,0,0);
                acc[rt][1] = __builtin_amdgcn_mfma_f32_16x16x32_bf16(a[rt], b1, acc[rt][1],0,0,0);
                acc[rt][2] = __builtin_amdgcn_mfma_f32_16x16x32_bf16(a[rt], b2, acc[rt][2],0,0,0);
                acc[rt][3] = __builtin_amdgcn_mfma_f32_16x16x32_bf16(a[rt], b3, acc[rt][3],0,0,0);
            }
        }
    }

    // C through LDS for coalesced bf16x8 stores
    __syncthreads();
    __bf16* C = &Abuf[0][0];              // 32 KB = [64][256] bf16
    #pragma unroll
    for (int rt = 0; rt < 4; ++rt)
        #pragma unroll
        for (int sl = 0; sl < 4; ++sl)
            #pragma unroll
            for (int r = 0; r < 4; ++r)
                C[(rt*16 + quad*4 + r)*256 + wave*64 + sl*16 + l15] = (__bf16)acc[rt][sl][r];
    __syncthreads();
    #pragma unroll
    for (int i = 0; i < 8; ++i) {
        int L = i*4096 + tid*16;          // byte in 32 KB
        int row = L >> 9, colb = L & 511;
        bf16x8 v = *(const bf16x8*)((const char*)C + L);
        *(bf16x8*)(XG + (arow0 + row)*4096 + ntile*256 + (colb >> 1)) = v;
    }
}

// ---------------- persistent recurrent kernel: 8 one-XCD groups of 32 blocks ----------------
// Group g = blk&7 (round-robin -> same XCD); block bl=blk>>3 owns gate-cols bl*128..+127
// (h-cols bl*32..+31) for the group's 8 batches. W_h-only in registers (2 slices/wave).
// x-projections precomputed (XG). Exchange protocol:
//   LOCAL mode (group verified same-XCD via HW_REG_XCC_ID vote): sc0 stores/polls at the
//     shared L2 (~200cy RTs). FALLBACK mode: agent-scope (L3) ops, store-only flags.
// Every spin loop carries a finite budget (SPIN_BUDGET polls, unreachable in normal
// operation): a true deadlock degrades to fast wrong-answer completion (passed:false
// + counters) instead of a silent harness hang.
__global__ void __launch_bounds__(256, 1) lstm_rnn(
    const __bf16* __restrict__ XG,    // [32768][4096] bf16
    const __bf16* __restrict__ wf,    // frag-swizzled [256][64][64][8]
    const float* __restrict__ bi, const float* __restrict__ bfg,
    const float* __restrict__ bc, const float* __restrict__ bo,
    __bf16* __restrict__ ring,        // [8 groups][128 slots][8][1024] bf16 = 16 MB
    int* __restrict__ bar,            // 64 x 16-int global rounds
    int* __restrict__ xcid,           // 256 ints
    int* __restrict__ flags,          // 8*32 x 16-int per-block epoch flags
    float* __restrict__ out)
{
    const int blk = blockIdx.x, tid = threadIdx.x;
    const int g = blk & 7, bl = blk >> 3;
    const int wave = tid >> 6, lane = tid & 63, l15 = lane & 15, quad = lane >> 4;

    // W_h fragments: slices bl*8 + wave*2 + {0,1}, h-part kc 32..63
    bf16x8 wfrag[2][32];
    {
        const __bf16* base0 = wf + (((size_t)(bl*8 + wave*2)*64 + 32)*64)*8;
        const __bf16* base1 = base0 + (size_t)64*64*8;
        #pragma unroll
        for (int kc = 0; kc < 32; ++kc) {
            wfrag[0][kc] = *(const bf16x8*)(base0 + (size_t)(kc*64 + lane)*8);
            wfrag[1][kc] = *(const bf16x8*)(base1 + (size_t)(kc*64 + lane)*8);
        }
    }

    int spin_budget = SPIN_BUDGET;   // shared across all waits; hits 0 only on deadlock

    // ---- round A: every block on every XCD flushes+invalidates its L2 ----
    __threadfence();
    __syncthreads();
    if (tid == 0)
        __hip_atomic_fetch_add(&bar[(blk & 63)*16], 1, __ATOMIC_RELAXED, __HIP_MEMORY_SCOPE_AGENT);
    if (tid < 64)
        while (__hip_atomic_load(&bar[tid*16], __ATOMIC_RELAXED, __HIP_MEMORY_SCOPE_AGENT) < 4
               && --spin_budget > 0)
            __builtin_amdgcn_s_sleep(2);
    __syncthreads();

    // ---- round B: publish XCC id, then group votes on same-XCD ----
    int myxcc;
    asm volatile("s_getreg_b32 %0, hwreg(HW_REG_XCC_ID)" : "=s"(myxcc));
    if (tid == 0)
        __hip_atomic_store(&xcid[blk], myxcc, __ATOMIC_RELAXED, __HIP_MEMORY_SCOPE_AGENT);
    __builtin_amdgcn_s_waitcnt(0);
    __syncthreads();
    if (tid == 0)
        __hip_atomic_fetch_add(&bar[(blk & 63)*16], 1, __ATOMIC_RELAXED, __HIP_MEMORY_SCOPE_AGENT);
    if (tid < 64)
        while (__hip_atomic_load(&bar[tid*16], __ATOMIC_RELAXED, __HIP_MEMORY_SCOPE_AGENT) < 8
               && --spin_budget > 0)
            __builtin_amdgcn_s_sleep(2);
    __syncthreads();

    __shared__ int modeflag;
    if (tid < 64) {
        int v = (lane < 32)
            ? __hip_atomic_load(&xcid[lane*8 + g], __ATOMIC_RELAXED, __HIP_MEMORY_SCOPE_AGENT) : 0;
        int v0 = __shfl(v, 0, 64);
        bool same = __all((lane < 32) ? (v == v0) : 1);
        if (tid == 0) modeflag = same ? 1 : 0;
    }
    __syncthreads();
    const bool localm = (modeflag != 0);

    u64* grbase = (u64*)ring + (size_t)g * 128 * 2048;   // 2048 u64 per 16KB slot
    int* gflags = flags + (size_t)g * 32 * 16;
    int* myflag = gflags + bl * 16;

    // ---- publish h0 = 0 into slot 0, then flag epoch 1 ----
    if (tid < 64) {
        u64* dst = grbase + (size_t)(tid >> 3)*256 + bl*8 + (tid & 7);
        if (localm) store64_sc0(dst, 0ULL);
        else __hip_atomic_store(dst, 0ULL, __ATOMIC_RELAXED, __HIP_MEMORY_SCOPE_AGENT);
    }
    __builtin_amdgcn_s_waitcnt(0);
    __syncthreads();
    if (tid == 0) {
        if (localm) store32_sc0(myflag, 1);
        else __hip_atomic_store(myflag, 1, __ATOMIC_RELAXED, __HIP_MEMORY_SCOPE_AGENT);
    }

    // pointwise ownership: thread -> (batch pb of 8, h-col phl of 32)
    const int pb = tid >> 5, phl = tid & 31;
    const int hcol = bl*32 + phl;
    const int bglob = g*8 + pb;
    const float bias_i = bi[hcol], bias_f = bfg[hcol],
                bias_c = bc[hcol], bias_o = bo[hcol];
    float c_reg = 0.f;

    __shared__ float gates[8*128];    // [batch][128 gate-cols of this block]
    __shared__ __bf16 hst[8][32];

    const __bf16* ringg = ring + (size_t)g * 128 * 8192;
    const __bf16* XGrow = XG + ((size_t)bglob*512)*4096 + bl*128 + phl*4;

    for (int t = 0; t < 512; ++t) {
        // prefetch this thread's 4 x-gate values (pure stream, off critical path)
        u64 xgb = *(const u64*)(XGrow + (size_t)t*4096);

        // ---- wait: all 32 member flags >= t+1 (wave 0, 1 flag/lane) ----
        const int tgt = t + 1;
        if (tid < 64) {
            if (localm) {
                for (;;) {
                    int v = (lane < 32) ? load32_sc0(gflags + lane*16) : tgt;
                    if (__all(v >= tgt) || --spin_budget <= 0) break;
                    __builtin_amdgcn_s_sleep(1);
                }
            } else {
                for (;;) {
                    int v = (lane < 32)
                        ? __hip_atomic_load(gflags + lane*16, __ATOMIC_RELAXED, __HIP_MEMORY_SCOPE_AGENT) : tgt;
                    if (__all(v >= tgt) || --spin_budget <= 0) break;
                    __builtin_amdgcn_s_sleep(2);
                }
            }
        }
        __syncthreads();

        // ---- h-part MFMA from ring slot (plain loads; L2-fresh in local mode) ----
        const __bf16* hrow = ringg + (size_t)(t & 127)*8192 + (size_t)(l15 & 7)*1024 + quad*8;
        f32x4 aA0{}, aB0{}, aA1{}, aB1{};
        #pragma unroll
        for (int kc = 0; kc < 16; ++kc) {
            bf16x8 a0 = *(const bf16x8*)(hrow + (2*kc)*32);
            bf16x8 a1 = *(const bf16x8*)(hrow + (2*kc + 1)*32);
            aA0 = __builtin_amdgcn_mfma_f32_16x16x32_bf16(a0, wfrag[0][2*kc],   aA0, 0,0,0);
            aB0 = __builtin_amdgcn_mfma_f32_16x16x32_bf16(a1, wfrag[0][2*kc+1], aB0, 0,0,0);
            aA1 = __builtin_amdgcn_mfma_f32_16x16x32_bf16(a0, wfrag[1][2*kc],   aA1, 0,0,0);
            aB1 = __builtin_amdgcn_mfma_f32_16x16x32_bf16(a1, wfrag[1][2*kc+1], aB1, 0,0,0);
        }
        // D rows quad*4+r = batches 0..7 -> quads 0,1 carry valid rows
        if (quad < 2) {
            #pragma unroll
            for (int r = 0; r < 4; ++r) {
                gates[(quad*4 + r)*128 + wave*32 + l15]      = aA0[r] + aB0[r];
                gates[(quad*4 + r)*128 + wave*32 + 16 + l15] = aA1[r] + aB1[r];
            }
        }
        __syncthreads();

        f32x4 gv = *(const f32x4*)&gates[pb*128 + phl*4];
        float gi = gv[0] + bf2f((unsigned short)(xgb))       + bias_i;
        float gf = gv[1] + bf2f((unsigned short)(xgb >> 16)) + bias_f;
        float gc = gv[2] + bf2f((unsigned short)(xgb >> 32)) + bias_c;
        float go = gv[3] + bf2f((unsigned short)(xgb >> 48)) + bias_o;
        float it = 1.f/(1.f + __expf(-gi));
        float ft = 1.f/(1.f + __expf(-gf));
        float ch = 2.f/(1.f + __expf(-2.f*gc)) - 1.f;
        float ot = 1.f/(1.f + __expf(-go));
        c_reg = ft*c_reg + it*ch;
        float th = 2.f/(1.f + __expf(-2.f*c_reg)) - 1.f;
        float hn = ot*th;
        hst[pb][phl] = (__bf16)hn;
        __syncthreads();   // hstage complete

        if (t < 511) {
            if (tid < 64) {   // wave 0 publishes; wave-level waitcnt covers all 64 stores
                u64 hv = ((const u64*)hst)[tid];
                u64* dst = grbase + (size_t)((t + 1) & 127)*2048
                           + (size_t)(tid >> 3)*256 + bl*8 + (tid & 7);
                if (localm) store64_sc0(dst, hv);
                else __hip_atomic_store(dst, hv, __ATOMIC_RELAXED, __HIP_MEMORY_SCOPE_AGENT);
                __builtin_amdgcn_s_waitcnt(0);
                if (lane == 0) {
                    if (localm) store32_sc0(myflag, t + 2);
                    else __hip_atomic_store(myflag, t + 2, __ATOMIC_RELAXED, __HIP_MEMORY_SCOPE_AGENT);
                }
            }
        }

        // out store deferred past publish (HBM ack off the critical path)
        __builtin_nontemporal_store(hn, &out[((size_t)bglob*512 + t)*1024 + hcol]);
        if (t == 511) {
            __builtin_nontemporal_store(hn,    &out[OUT_HT + bglob*1024 + hcol]);
            __builtin_nontemporal_store(c_reg, &out[OUT_CT + bglob*1024 + hcol]);
        }
    }
}

extern "C" void kernel_launch(void* const* d_in, const int* in_sizes, int n_in,
                              void* d_out, int out_size, void* d_ws, size_t ws_size,
                              hipStream_t stream) {
    const float* x   = (const float*)d_in[0];
    const float* Wxi = (const float*)d_in[1];
    const float* Whi = (const float*)d_in[2];
    const float* bi  = (const float*)d_in[3];
    const float* Wxf = (const float*)d_in[4];
    const float* Whf = (const float*)d_in[5];
    const float* bfg = (const float*)d_in[6];
    const float* Wxc = (const float*)d_in[7];
    const float* Whc = (const float*)d_in[8];
    const float* bc  = (const float*)d_in[9];
    const float* Wxo = (const float*)d_in[10];
    const float* Who = (const float*)d_in[11];
    const float* bo  = (const float*)d_in[12];
    float* out = (float*)d_out;

    char* ws = (char*)d_ws;
    __bf16* wcombF = (__bf16*)ws;                        // 16 MB
    __bf16* xbf    = (__bf16*)(ws + (16ll << 20));       // 64 MB (GEMM input)
    __bf16* ring   = (__bf16*)(ws + (16ll << 20));       // 16 MB, aliases xbf (used after xgemm)
    __bf16* XG     = (__bf16*)(ws + (80ll << 20));       // 256 MB x-projections (bf16)
    char*   ctrl   = ws + (336ll << 20);
    int* bar   = (int*)ctrl;                             // 4 KB
    int* xcid  = (int*)(ctrl + 4096);                    // 1 KB
    int* flags = (int*)(ctrl + 8192);                    // 16 KB

    hipMemsetAsync(ctrl, 0, 32768, stream);

    hipLaunchKernelGGL(convert_x, dim3(32768), dim3(256), 0, stream,
                       (const float4*)x, (bf16x4*)xbf);
    hipLaunchKernelGGL(build_w, dim3(32768), dim3(256), 0, stream,
                       Wxi, Whi, Wxf, Whf, Wxc, Whc, Wxo, Who, wcombF);
    hipLaunchKernelGGL(xgemm, dim3(8192), dim3(256), 0, stream,
                       xbf, wcombF, XG);
    hipLaunchKernelGGL(lstm_rnn, dim3(256), dim3(256), 0, stream,
                       XG, wcombF, bi, bfg, bc, bo, ring, bar, xcid, flags, out);
}